// Round 1
// baseline (434.315 us; speedup 1.0000x reference)
//
#include <hip/hip_runtime.h>

#define D_MODEL 768
#define BN 16
#define NROWS 32768
#define SCALE 0.1f
#define LN_EPS 1e-5f
#define TPB 256
#define JPT 3                       // d's per thread: 768/256
#define ROWS_PER_BLOCK 32
#define NBLOCKS (NROWS / ROWS_PER_BLOCK)   // 1024

__global__ __launch_bounds__(TPB, 2)
void adapter_fused(const float* __restrict__ x,
                   const float* __restrict__ gamma,
                   const float* __restrict__ beta,
                   const float* __restrict__ w_down,
                   const float* __restrict__ b_down,
                   const float* __restrict__ w_up,
                   const float* __restrict__ b_up,
                   float* __restrict__ out)
{
    __shared__ float s_ln[4][2];      // per-wave (s1, s2)
    __shared__ float s_dpart[4][BN];  // per-wave down partials
    __shared__ float s_down[BN];      // final relu'd down vector

    const int t    = threadIdx.x;
    const int wave = t >> 6;
    const int lane = t & 63;

    // ---- one-time per block: weights & params into registers ----
    float wd[JPT][BN];   // w_down[d][k], d = t + 256*j   (row-major (768,16))
    float wu[JPT][BN];   // w_up[k][d]                    (row-major (16,768))
    float g[JPT], bt[JPT], bu[JPT];
    #pragma unroll
    for (int j = 0; j < JPT; ++j) {
        const int d = t + TPB * j;
        const float4* wrow = (const float4*)(w_down + (size_t)d * BN);
        #pragma unroll
        for (int q = 0; q < 4; ++q) {
            float4 v = wrow[q];
            wd[j][q*4+0] = v.x; wd[j][q*4+1] = v.y;
            wd[j][q*4+2] = v.z; wd[j][q*4+3] = v.w;
        }
        #pragma unroll
        for (int k = 0; k < BN; ++k)
            wu[j][k] = w_up[k * D_MODEL + d];
        g[j]  = gamma[d];
        bt[j] = beta[d];
        bu[j] = b_up[d];
    }
    const float bd = b_down[t & (BN - 1)];
    const float inv_d = 1.0f / (float)D_MODEL;

    const int row0 = blockIdx.x * ROWS_PER_BLOCK;

    for (int r = 0; r < ROWS_PER_BLOCK; ++r) {
        const float* __restrict__ xr   = x   + (size_t)(row0 + r) * D_MODEL;
        float* __restrict__       orow = out + (size_t)(row0 + r) * D_MODEL;

        float xv[JPT];
        #pragma unroll
        for (int j = 0; j < JPT; ++j) xv[j] = xr[t + TPB * j];

        // ---- LayerNorm stats: wave butterfly + cross-wave via LDS ----
        float s1 = 0.f, s2 = 0.f;
        #pragma unroll
        for (int j = 0; j < JPT; ++j) { s1 += xv[j]; s2 = fmaf(xv[j], xv[j], s2); }
        #pragma unroll
        for (int m = 32; m >= 1; m >>= 1) {
            s1 += __shfl_xor(s1, m, 64);
            s2 += __shfl_xor(s2, m, 64);
        }
        if (lane == 0) { s_ln[wave][0] = s1; s_ln[wave][1] = s2; }
        __syncthreads();
        const float S1 = s_ln[0][0] + s_ln[1][0] + s_ln[2][0] + s_ln[3][0];
        const float S2 = s_ln[0][1] + s_ln[1][1] + s_ln[2][1] + s_ln[3][1];
        const float mean = S1 * inv_d;
        const float var  = fmaf(S2, inv_d, -(mean * mean));
        const float rs   = rsqrtf(var + LN_EPS);

        // ---- normalize + down-proj partials (48 FMA) ----
        float xn[JPT];
        #pragma unroll
        for (int j = 0; j < JPT; ++j)
            xn[j] = fmaf((xv[j] - mean) * rs, g[j], bt[j]);

        float p[BN];
        #pragma unroll
        for (int k = 0; k < BN; ++k) p[k] = 0.f;
        #pragma unroll
        for (int j = 0; j < JPT; ++j) {
            #pragma unroll
            for (int k = 0; k < BN; ++k)
                p[k] = fmaf(xn[j], wd[j][k], p[k]);
        }

        // ---- split-butterfly: 16-vector reduced across 16 lanes in 15 shfls;
        //      after this, each lane holds k = lane&15 summed over its 16-group ----
        #pragma unroll
        for (int m = 8; m >= 1; m >>= 1) {
            const bool upper = (lane & m) != 0;
            #pragma unroll
            for (int i = 0; i < m; ++i) {
                float send = upper ? p[i] : p[i + m];
                float recv = __shfl_xor(send, m, 64);
                p[i] = (upper ? p[i + m] : p[i]) + recv;
            }
        }
        float v = p[0];
        v += __shfl_xor(v, 16, 64);
        v += __shfl_xor(v, 32, 64);   // wave-level sum for k = lane&15

        if (lane < BN) s_dpart[wave][lane] = v;
        __syncthreads();
        if (t < BN) {
            float dsum = s_dpart[0][t] + s_dpart[1][t] + s_dpart[2][t] + s_dpart[3][t] + bd;
            s_down[t] = fmaxf(dsum, 0.f);   // ReLU
        }
        __syncthreads();

        // ---- broadcast down vector (LDS same-address reads broadcast free) ----
        float dn[BN];
        const float4* dp = (const float4*)s_down;
        #pragma unroll
        for (int q = 0; q < 4; ++q) {
            float4 dv = dp[q];
            dn[q*4+0] = dv.x; dn[q*4+1] = dv.y; dn[q*4+2] = dv.z; dn[q*4+3] = dv.w;
        }

        // ---- up-proj (48 FMA) + scale + residual, coalesced store ----
        #pragma unroll
        for (int j = 0; j < JPT; ++j) {
            float acc = bu[j];
            #pragma unroll
            for (int k = 0; k < BN; ++k)
                acc = fmaf(dn[k], wu[j][k], acc);
            orow[t + TPB * j] = fmaf(SCALE, acc, xv[j]);
        }
    }
}

extern "C" void kernel_launch(void* const* d_in, const int* in_sizes, int n_in,
                              void* d_out, int out_size, void* d_ws, size_t ws_size,
                              hipStream_t stream) {
    const float* x       = (const float*)d_in[0];
    const float* gamma   = (const float*)d_in[1];
    const float* beta    = (const float*)d_in[2];
    const float* w_down  = (const float*)d_in[3];
    const float* b_down  = (const float*)d_in[4];
    const float* w_up    = (const float*)d_in[5];
    const float* b_up    = (const float*)d_in[6];
    float* out = (float*)d_out;

    adapter_fused<<<NBLOCKS, TPB, 0, stream>>>(x, gamma, beta, w_down, b_down,
                                               w_up, b_up, out);
}